// Round 9
// baseline (5232.155 us; speedup 1.0000x reference)
//
#include <hip/hip_runtime.h>

#define NB 64
#define NT 1024
#define DIN 12
#define NH 256
#define NG 1024
#define NCLS 17
#define TCL 128
#define NCHUNK 8
#define XPS ((size_t)2 * NB * TCL * NG)   // floats per xp1 chunk buffer

typedef _Float16 f16;
typedef __attribute__((ext_vector_type(2))) _Float16 half2_t;
typedef __attribute__((ext_vector_type(8))) _Float16 f16x8;
typedef __attribute__((ext_vector_type(4))) float f32x4;
typedef unsigned int uint;
typedef unsigned short ushort;

__device__ __forceinline__ float sigm(float v) { return 1.0f / (1.0f + __expf(-v)); }
__device__ __forceinline__ float tanh_(float v) {
    v = fminf(fmaxf(v, -15.0f), 15.0f);
    float e = __expf(2.0f * v);
    return (e - 1.0f) / (e + 1.0f);
}
__device__ __forceinline__ float dot2(uint w, uint h, float c) {
    return __builtin_amdgcn_fdot2(__builtin_bit_cast(half2_t, w),
                                  __builtin_bit_cast(half2_t, h), c, false);
}
__device__ __forceinline__ uint pack16(float a, float b) {
    union { f16 h[2]; uint u; } cv; cv.h[0] = (f16)a; cv.h[1] = (f16)b; return cv.u;
}
__device__ __forceinline__ uint pkrtz(float a, float b) {
    return __builtin_bit_cast(uint, __builtin_amdgcn_cvt_pkrtz(a, b));
}
__device__ __forceinline__ ushort hbits(f16 v) {
    union { f16 h; ushort u; } cv; cv.h = v; return cv.u;
}

// ---------------------------------------------------------------------------
// k_prep: pack fp16 weights for the K-split 512-thread recurrence.
// ld = layer*2+dir. Lane (u,p): gates rows q*256+u (q=0..3), kp = 64p + kpl:
//  Wkv [ld][q][p][u][kpl 0..15]          (VGPR cache, 64 uints/lane)
//  Wka [ld][q][p][u][kpl 16..47]         (AGPR cache, 128 uints/lane)
//  Wkl [ld][q][g4 0..3][p][u] uint4      (LDS cache, kpl = 48+4g4+j, 131 KB)
//  wih0p [dir][q][p][u][dp 0..2]         packed half2, dims d = 6p+2dp(+1)
//  wih1h fp16 copy of w_ih1; bsum1 = b_ih1 + b_hh1
// ---------------------------------------------------------------------------
__global__ void k_prep(const float* __restrict__ w_hh0, const float* __restrict__ w_hh1,
                       const float* __restrict__ w_ih0, const float* __restrict__ w_ih1,
                       const float* __restrict__ b_ih1, const float* __restrict__ b_hh1,
                       uint* __restrict__ Wkv, uint* __restrict__ Wka,
                       uint* __restrict__ Wkl, uint* __restrict__ wih0p,
                       f16* __restrict__ wih1h, float* __restrict__ bsum1) {
    int i = blockIdx.x * 256 + threadIdx.x;
    if (i < 131072) {                       // Wkv
        int kpi = i & 15; int r = i >> 4;
        int u = r & 255, pp = (r >> 8) & 1, q = (r >> 9) & 3, ld = r >> 11;
        const float* row = (ld < 2 ? w_hh0 : w_hh1) + (size_t)(ld & 1) * NG * NH
                         + (size_t)(q * 256 + u) * NH;
        int kp = 64 * pp + kpi;
        Wkv[i] = pack16(row[2 * kp], row[2 * kp + 1]);
    }
    if (i < 262144) {                       // Wka
        int kpi = i & 31; int r = i >> 5;
        int u = r & 255, pp = (r >> 8) & 1, q = (r >> 9) & 3, ld = r >> 11;
        const float* row = (ld < 2 ? w_hh0 : w_hh1) + (size_t)(ld & 1) * NG * NH
                         + (size_t)(q * 256 + u) * NH;
        int kp = 64 * pp + 16 + kpi;
        Wka[i] = pack16(row[2 * kp], row[2 * kp + 1]);
    }
    if (i < 131072) {                       // Wkl
        int j = i & 3; int r4 = i >> 2;     // uint4 idx = (((ld*4+q)*4+g4)*2+pp)*256+u
        int u = r4 & 255, pp = (r4 >> 8) & 1, g4 = (r4 >> 9) & 3;
        int q = (r4 >> 11) & 3, ld = r4 >> 13;
        const float* row = (ld < 2 ? w_hh0 : w_hh1) + (size_t)(ld & 1) * NG * NH
                         + (size_t)(q * 256 + u) * NH;
        int kp = 64 * pp + 48 + 4 * g4 + j;
        Wkl[i] = pack16(row[2 * kp], row[2 * kp + 1]);
    }
    if (i < 12288) {                        // wih0p
        int dp = i % 3; int r = i / 3;
        int u = r & 255, pp = (r >> 8) & 1, q = (r >> 9) & 3, dd = r >> 11;
        const float* row = w_ih0 + ((size_t)dd * NG + q * 256 + u) * DIN;
        int d0 = 6 * pp + 2 * dp;
        wih0p[i] = pack16(row[d0], row[d0 + 1]);
    }
    if (i < 2 * NG * 2 * NH) wih1h[i] = (f16)w_ih1[i];
    if (i < 2 * NG) bsum1[i] = b_ih1[i] + b_hh1[i];
}

// ---------------------------------------------------------------------------
// rec_seq<LAYER>: one block per (dir, batch), 512 threads (8 waves, 2/SIMD).
// Lane (u,p) computes 4 gate-partials of unit u over k in [128p, 128p+128).
// Whh fully CU-resident: 64 VGPR + 128 AGPR uints/lane + 131 KB LDS.
// p=1 publishes partials via 4 KB LDS; p=0 combines, activates, publishes h
// (single fp16 — validated round 8). Two barriers/step; no inter-block comms.
// ---------------------------------------------------------------------------
template <int LAYER>
__device__ void rec_seq(char* smem, int rb, int chunk, int nsteps,
                        const uint* __restrict__ Wkv, const uint* __restrict__ Wka,
                        const uint4* __restrict__ Wkl, const uint* __restrict__ wih0p,
                        const float* __restrict__ b_ih0, const float* __restrict__ b_hh0,
                        const float* __restrict__ x, const float* __restrict__ xp1,
                        f16* __restrict__ out0h,
                        float* __restrict__ hst, float* __restrict__ cst,
                        float* __restrict__ hsm) {
    uint4* wlds4 = (uint4*)smem;                     // [q][g4][p][u] 8192 uint4 = 131 KB
    float* zx = (float*)(smem + 131072);             // [u][q] 4 KB
    ushort* hs16 = (ushort*)(smem + 135168);         // [256] fp16 h
    const int tid = threadIdx.x;
    const int u = tid & 255, p = tid >> 8;
    const int dir = rb >> 6, b = rb & 63;
    const int ld = LAYER * 2 + dir;

    for (int n = tid; n < 8192; n += 512) wlds4[n] = Wkl[ld * 8192 + n];

    // VGPR weights (kpl 0..15)
    uint4 wrv[4][4];
    #pragma unroll
    for (int q = 0; q < 4; ++q) {
        const uint* src = Wkv + (size_t)((((ld * 4 + q) * 2 + p) * 256) + u) * 16;
        #pragma unroll
        for (int gi = 0; gi < 4; ++gi) wrv[q][gi] = *(const uint4*)(src + gi * 4);
    }
    // AGPR weights (kpl 16..47): 128 uints/lane
    uint aw[128];
    #pragma unroll
    for (int q = 0; q < 4; ++q) {
        const uint* src = Wka + (size_t)((((ld * 4 + q) * 2 + p) * 256) + u) * 32;
        #pragma unroll
        for (int ga = 0; ga < 8; ++ga) {
            uint4 v = *(const uint4*)(src + ga * 4);
            asm volatile("v_accvgpr_write_b32 %0, %1" : "=a"(aw[(q * 8 + ga) * 4 + 0]) : "v"(v.x));
            asm volatile("v_accvgpr_write_b32 %0, %1" : "=a"(aw[(q * 8 + ga) * 4 + 1]) : "v"(v.y));
            asm volatile("v_accvgpr_write_b32 %0, %1" : "=a"(aw[(q * 8 + ga) * 4 + 2]) : "v"(v.z));
            asm volatile("v_accvgpr_write_b32 %0, %1" : "=a"(aw[(q * 8 + ga) * 4 + 3]) : "v"(v.w));
        }
    }

    uint wihr[12];
    if (LAYER == 0) {
        #pragma unroll
        for (int q = 0; q < 4; ++q) {
            const uint* src = wih0p + (size_t)((((dir * 4 + q) * 2 + p) * 256) + u) * 3;
            wihr[q * 3 + 0] = src[0]; wihr[q * 3 + 1] = src[1]; wihr[q * 3 + 2] = src[2];
        }
    }
    float bias[4] = {0.f, 0.f, 0.f, 0.f};
    if (LAYER == 0 && p == 0) {
        #pragma unroll
        for (int q = 0; q < 4; ++q)
            bias[q] = b_ih0[dir * NG + q * 256 + u] + b_hh0[dir * NG + q * 256 + u];
    }

    const int sidx = (ld * NB + b) * NH + u;
    float cv = 0.f, hv = 0.f, hsv = 0.f;
    if (p == 0) {
        if (chunk != 0) {
            cv = cst[sidx]; hv = hst[sidx];
            if (LAYER == 1) hsv = hsm[(dir * NB + b) * NH + u];
        }
        hs16[u] = hbits((f16)hv);
    }
    __syncthreads();

    #pragma unroll 1
    for (int it = 0; it < nsteps; ++it) {
        const uint4* Hh = ((const uint4*)hs16) + 16 * p;   // this lane's half of h

        float4 xq4 = {0.f, 0.f, 0.f, 0.f};
        float xvp[6];
        if (LAYER == 1) {
            if (p == 0)
                xq4 = *(const float4*)(xp1 + (((size_t)dir * NB + b) * TCL + it) * NG + u * 4);
        } else {
            const int t = dir ? (NT - 1 - it) : it;
            const float4* xp = (const float4*)(x + ((size_t)b * NT + t) * DIN);
            float4 A = xp[0], B4 = xp[1], C4 = xp[2];
            if (p == 0) { xvp[0]=A.x; xvp[1]=A.y; xvp[2]=A.z; xvp[3]=A.w; xvp[4]=B4.x; xvp[5]=B4.y; }
            else        { xvp[0]=B4.z; xvp[1]=B4.w; xvp[2]=C4.x; xvp[3]=C4.y; xvp[4]=C4.z; xvp[5]=C4.w; }
        }

        float ah[4] = {0.f, 0.f, 0.f, 0.f};

        // ---- VGPR region: kpl 0..15 ----
        #pragma unroll
        for (int gi = 0; gi < 4; ++gi) {
            uint4 H = Hh[gi];
            #pragma unroll
            for (int q = 0; q < 4; ++q) {
                uint4 w = wrv[q][gi];
                ah[q] = dot2(w.x, H.x, ah[q]);
                ah[q] = dot2(w.y, H.y, ah[q]);
                ah[q] = dot2(w.z, H.z, ah[q]);
                ah[q] = dot2(w.w, H.w, ah[q]);
            }
        }
        // ---- AGPR region: kpl 16..47 ----
        #pragma unroll
        for (int ga = 0; ga < 8; ++ga) {
            uint4 H = Hh[4 + ga];
            #pragma unroll
            for (int q = 0; q < 4; ++q) {
                uint w0, w1, w2, w3;
                asm volatile("v_accvgpr_read_b32 %0, %1" : "=v"(w0) : "a"(aw[(q * 8 + ga) * 4 + 0]));
                asm volatile("v_accvgpr_read_b32 %0, %1" : "=v"(w1) : "a"(aw[(q * 8 + ga) * 4 + 1]));
                asm volatile("v_accvgpr_read_b32 %0, %1" : "=v"(w2) : "a"(aw[(q * 8 + ga) * 4 + 2]));
                asm volatile("v_accvgpr_read_b32 %0, %1" : "=v"(w3) : "a"(aw[(q * 8 + ga) * 4 + 3]));
                ah[q] = dot2(w0, H.x, ah[q]);
                ah[q] = dot2(w1, H.y, ah[q]);
                ah[q] = dot2(w2, H.z, ah[q]);
                ah[q] = dot2(w3, H.w, ah[q]);
            }
        }
        // ---- LDS region: kpl 48..63 ----
        #pragma unroll
        for (int g4 = 0; g4 < 4; ++g4) {
            uint4 H = Hh[12 + g4];
            #pragma unroll
            for (int q = 0; q < 4; ++q) {
                uint4 w = wlds4[((q * 4 + g4) * 2 + p) * 256 + u];
                ah[q] = dot2(w.x, H.x, ah[q]);
                ah[q] = dot2(w.y, H.y, ah[q]);
                ah[q] = dot2(w.z, H.z, ah[q]);
                ah[q] = dot2(w.w, H.w, ah[q]);
            }
        }
        // ---- L0 input projection (each lane adds its 6 dims) ----
        if (LAYER == 0) {
            uint xph[3];
            #pragma unroll
            for (int dp = 0; dp < 3; ++dp) xph[dp] = pkrtz(xvp[2 * dp], xvp[2 * dp + 1]);
            #pragma unroll
            for (int q = 0; q < 4; ++q) {
                ah[q] = dot2(wihr[q * 3 + 0], xph[0], ah[q]);
                ah[q] = dot2(wihr[q * 3 + 1], xph[1], ah[q]);
                ah[q] = dot2(wihr[q * 3 + 2], xph[2], ah[q]);
            }
        }

        if (p == 1) *(float4*)(zx + u * 4) = make_float4(ah[0], ah[1], ah[2], ah[3]);
        __syncthreads();   // B: partials visible

        if (p == 0) {
            float4 zo = *(const float4*)(zx + u * 4);
            float z0 = ah[0] + zo.x + bias[0] + xq4.x;
            float z1 = ah[1] + zo.y + bias[1] + xq4.y;
            float z2 = ah[2] + zo.z + bias[2] + xq4.z;
            float z3 = ah[3] + zo.w + bias[3] + xq4.w;
            cv = sigm(z1) * cv + sigm(z0) * tanh_(z2);
            hv = sigm(z3) * tanh_(cv);
            if (LAYER == 1) hsv += hv;
            f16 hi = (f16)hv;
            hs16[u] = hbits(hi);
            if (LAYER == 0) {
                const int t = dir ? (NT - 1 - it) : it;
                out0h[((size_t)b * NT + t) * 512 + dir * 256 + u] = hi;
            }
        }
        __syncthreads();   // A: h_{t+1} visible
    }

    if (p == 0) {
        cst[sidx] = cv; hst[sidx] = hv;
        if (LAYER == 1) hsm[(dir * NB + b) * NH + u] = hsv;
    }
}

// ---------------------------------------------------------------------------
// proj_role (chunk c): fp16 MFMA 16x16x32 direct-from-global (layout verified
// rounds 6-8). 128 role-blocks x 8 waves; wave owns one 16-row m-tile.
// Stores xp1 as [t][unit][gate] so rec1's per-step fetch is one float4.
// ---------------------------------------------------------------------------
__device__ void proj_role(int pb, int c,
                          const f16* __restrict__ out0h, const f16* __restrict__ wih1h,
                          const float* __restrict__ bsum1, float* __restrict__ xp1) {
    const int tid = threadIdx.x;
    const int w = tid >> 6, l = tid & 63;
    const int lane16 = l & 15, quad = l >> 4;
    const int mtg = pb * 8 + w;                // 0..1023
    const int dirt = mtg >> 9;
    const int mtl = mtg & 511;

    const int ra = mtl * 16 + lane16;          // row over b(64) x tl(128)
    const int ab = ra >> 7, tla = ra & 127;
    const int ta = dirt ? (NT - 1 - c * TCL - tla) : (c * TCL + tla);
    const f16* Arow = out0h + ((size_t)ab * NT + ta) * 512 + quad * 8;

    uint4 afr[16];
    #pragma unroll
    for (int kt = 0; kt < 16; ++kt) afr[kt] = *(const uint4*)(Arow + kt * 32);

    int ob[4], otl[4];
    #pragma unroll
    for (int reg = 0; reg < 4; ++reg) {
        int rr = mtl * 16 + quad * 4 + reg;
        ob[reg] = rr >> 7; otl[reg] = rr & 127;
    }

    const f16* Bbase = wih1h + (size_t)dirt * NG * 512 + quad * 8;

    #pragma unroll 1
    for (int nt = 0; nt < 64; ++nt) {
        const int col = nt * 16 + lane16;
        const f16* Brow = Bbase + (size_t)col * 512;
        float bias = bsum1[dirt * NG + col];

        f32x4 acc = {0.f, 0.f, 0.f, 0.f};
        #pragma unroll
        for (int kt = 0; kt < 16; ++kt) {
            uint4 bv = *(const uint4*)(Brow + kt * 32);
            acc = __builtin_amdgcn_mfma_f32_16x16x32_f16(
                __builtin_bit_cast(f16x8, afr[kt]),
                __builtin_bit_cast(f16x8, bv), acc, 0, 0, 0);
        }
        const int ucol = col & 255, qcol = col >> 8;
        #pragma unroll
        for (int reg = 0; reg < 4; ++reg) {
            xp1[((size_t)(dirt * NB + ob[reg]) * TCL + otl[reg]) * NG
                + ucol * 4 + qcol] = acc[reg] + bias;
        }
    }
}

// ---------------------------------------------------------------------------
// Phase A: layer 0, full 1024 steps, 128 independent blocks x 512 threads.
// ---------------------------------------------------------------------------
__global__ __launch_bounds__(512) void k_rec0(
    const uint* __restrict__ Wkv, const uint* __restrict__ Wka,
    const uint4* __restrict__ Wkl, const uint* __restrict__ wih0p,
    const float* __restrict__ b_ih0, const float* __restrict__ b_hh0,
    const float* __restrict__ x, f16* __restrict__ out0h,
    float* __restrict__ hst, float* __restrict__ cst) {
    extern __shared__ __align__(16) char smem[];
    rec_seq<0>(smem, blockIdx.x, 0, NT, Wkv, Wka, Wkl, wih0p, b_ih0, b_hh0,
               x, nullptr, out0h, hst, cst, nullptr);
}

// ---------------------------------------------------------------------------
// Phase B launch j: blocks 0..127 = rec1 chunk j-1; blocks 128..255 = proj
// chunk j (legal: out0h complete after phase A). Double-buffered xp1.
// ---------------------------------------------------------------------------
__global__ __launch_bounds__(512) void k_pipe(
    int j,
    const uint* __restrict__ Wkv, const uint* __restrict__ Wka,
    const uint4* __restrict__ Wkl,
    const f16* __restrict__ out0h, const f16* __restrict__ wih1h,
    const float* __restrict__ bsum1, float* __restrict__ xp1,
    float* __restrict__ hst, float* __restrict__ cst, float* __restrict__ hsm) {
    extern __shared__ __align__(16) char smem[];
    const int bid = blockIdx.x;
    if (bid < 128) {
        const int cc = j - 1;
        if (cc >= 0 && cc < NCHUNK)
            rec_seq<1>(smem, bid, cc, TCL, Wkv, Wka, Wkl, nullptr, nullptr, nullptr,
                       nullptr, xp1 + (size_t)(cc & 1) * XPS, nullptr, hst, cst, hsm);
    } else {
        const int cp = j;
        if (cp < NCHUNK)
            proj_role(bid - 128, cp, out0h, wih1h, bsum1,
                      xp1 + (size_t)(cp & 1) * XPS);
    }
}

// ---------------------------------------------------------------------------
__global__ void k_fc(const float* __restrict__ hsm, const float* __restrict__ fc_w,
                     const float* __restrict__ fc_b, float* __restrict__ out) {
    const int b = blockIdx.x;
    const int n = threadIdx.x;
    if (n >= NCLS) return;
    float acc = fc_b[n];
    const float inv = 1.0f / (float)NT;
    for (int k = 0; k < 2 * NH; ++k) {
        float pv = hsm[((k >> 8) * NB + b) * NH + (k & 255)];
        acc += (pv * inv) * fc_w[n * 2 * NH + k];
    }
    out[b * NCLS + n] = acc;
}

// ---------------------------------------------------------------------------
extern "C" void kernel_launch(void* const* d_in, const int* in_sizes, int n_in,
                              void* d_out, int out_size, void* d_ws, size_t ws_size,
                              hipStream_t stream) {
    const float* x     = (const float*)d_in[0];
    const float* w_ih0 = (const float*)d_in[1];
    const float* w_hh0 = (const float*)d_in[2];
    const float* b_ih0 = (const float*)d_in[3];
    const float* b_hh0 = (const float*)d_in[4];
    const float* w_ih1 = (const float*)d_in[5];
    const float* w_hh1 = (const float*)d_in[6];
    const float* b_ih1 = (const float*)d_in[7];
    const float* b_hh1 = (const float*)d_in[8];
    const float* fc_w  = (const float*)d_in[9];
    const float* fc_b  = (const float*)d_in[10];
    float* out = (float*)d_out;

    char* ws = (char*)d_ws;
    uint* Wkv   = (uint*)ws;                      // 131072 u
    uint* Wka   = Wkv + 131072;                   // 262144 u
    uint* Wkl   = Wka + 262144;                   // 131072 u
    uint* wih0p = Wkl + 131072;                   // 12288 u
    f16* wih1h  = (f16*)(wih0p + 12288);          // 1048576 h = 2 MB
    float* bsum1 = (float*)(wih1h + 1048576);     // 2048 f
    float* hst  = bsum1 + 2048;                   // 65536 f
    float* cst  = hst + 65536;                    // 65536 f
    float* hsm  = cst + 65536;                    // 32768 f
    float* xp1  = hsm + 32768;                    // 2 x 16777216 f = 128 MB
    f16* out0h  = (f16*)(xp1 + 2 * XPS);          // 33554432 h = 64 MB

    k_prep<<<dim3(4096), dim3(256), 0, stream>>>(
        w_hh0, w_hh1, w_ih0, w_ih1, b_ih1, b_hh1,
        Wkv, Wka, Wkl, wih0p, wih1h, bsum1);

    k_rec0<<<dim3(128), dim3(512), 135680, stream>>>(
        Wkv, Wka, (const uint4*)Wkl, wih0p, b_ih0, b_hh0, x, out0h, hst, cst);

    for (int j = 0; j <= NCHUNK; ++j) {
        k_pipe<<<dim3(256), dim3(512), 135680, stream>>>(
            j, Wkv, Wka, (const uint4*)Wkl, out0h, wih1h, bsum1, xp1, hst, cst, hsm);
    }

    k_fc<<<dim3(64), dim3(32), 0, stream>>>(hsm, fc_w, fc_b, out);
}